// Round 8
// baseline (124.572 us; speedup 1.0000x reference)
//
#include <hip/hip_runtime.h>

// SoftRAM attention: S=128, B=256 bits, H=16 heads, NB=12 bits/neuron, PB=7.
// addr(i,j,h,n) = aq_i | ak_j | ap_{i-j}, disjoint bit groups per (h,n).
//
// R16: DIAGNOSTIC ROUND. R15 (split-row, 32 waves/CU) was the third TLP null;
// softram sits at ~34-35us while bottom-up accounting says ~15-20. Per the
// ablate-first rule, this round keeps the verified R15 pipeline byte-identical
// (real output path) and appends ONE extra dispatch to scratch:
// softram<LOADS=0> == same kernel with the 64MB memory stream replaced by a
// 3-VALU register pattern (conns/tokens/class/pack/repack/sweep/store all
// live -> no DCE). dur_us delta vs 108.3 = compute-only time C:
//   C>=28 -> compute/issue-bound -> attack repack ballots + shfl chains.
//   C<=12 -> stream-bound at ~2TB/s despite coalescing -> reshape load path.
//   else  -> phases serialize -> attack overlap.

#define S 128
#define B 256
#define H 16
#define NB 12

__device__ __forceinline__ unsigned sig(unsigned x) {
    return x ^ ((x >> 3) & 0x70u) ^ ((x >> 6) & 0x70u);
}

// token bit c lives at packed word TW(c), bit TP(c)
#define TW(c) ((((c) & 3) << 1) + ((c) >> 7))
#define TP(c) (((c) >> 2) & 31)

__global__ __launch_bounds__(256) void pack_kernel(
    const int* __restrict__ tokens,        // [S,B] 0/1
    unsigned* __restrict__ tokP)           // [8][S] packed
{
    const int wid  = threadIdx.x >> 6;
    const int lane = threadIdx.x & 63;
    const int4* tp = (const int4*)tokens;
    #pragma unroll
    for (int r = 0; r < 4; ++r) {
        int i = blockIdx.x * 16 + wid * 4 + r;
        int4 x = tp[i * 64 + lane];        // coalesced: full row of 256 ints
        unsigned long long B0 = __ballot((x.x & 1) != 0);  // bit l = tok[4l+0]
        unsigned long long B1 = __ballot((x.y & 1) != 0);
        unsigned long long B2 = __ballot((x.z & 1) != 0);
        unsigned long long B3 = __ballot((x.w & 1) != 0);
        int c = lane >> 1;                 // word index = comp*2 + half
        unsigned long long s01 = (c & 1) ? B1 : B0;
        unsigned long long s23 = (c & 1) ? B3 : B2;
        unsigned long long s   = (c & 2) ? s23 : s01;
        unsigned word = (lane & 1) ? (unsigned)(s >> 32) : (unsigned)s;
        if (lane < 8) tokP[lane * 128 + i] = word;
    }
}

template<int LOADS>
__global__ __launch_bounds__(256, 8) void softram_kernel(
    const unsigned* __restrict__ tokP,     // [8][S] packed tokens
    const float* __restrict__ memory,      // [H,B,4096]
    const int* __restrict__ connections,   // [H,B,NB]
    unsigned long long* __restrict__ pres) // [4096][2] result bits per row
{
    const int tid  = threadIdx.x;
    const int wid  = tid >> 6;
    const int rs   = wid >> 1;             // row slot in block (0/1)
    const int sub  = wid & 1;              // half (0: lo, 1: hi)
    const int r    = blockIdx.x * 2 + rs;  // row = h*256+n
    const int lane = tid & 63;

    __shared__ __align__(16) unsigned char      bytetab[2][4096]; // 8 KB
    __shared__ __align__(16) unsigned int       tokT[8 * S];      // 4 KB
    __shared__ __align__(16) unsigned short     akT[2][S];        // key cls / sig(ak)
    __shared__ __align__(16) unsigned short     apt[2][S];        // sig(ap) (fb)
    __shared__ __align__(16) unsigned short     aqs[2][S];        // sig(aq) (fb)
    __shared__ __align__(16) unsigned long long wsh[2][64];       // 1 KB bit-LUT
    __shared__ unsigned long long baseS[2];                       // prefix carry
    __shared__ unsigned long long fbu[2];                         // fb upper part

    unsigned char* __restrict__ bt = bytetab[rs];

    // ---- own 8KB half-row, 4-deep register ring ----
    const float4* mp = (const float4*)(memory + ((size_t)r << 12));
    float4 va[4];
    #pragma unroll
    for (int t = 0; t < 4; ++t) {
        if (LOADS) {
            va[t] = mp[lane + 64 * (sub * 8 + t)];
        } else {
            unsigned u = (unsigned)lane * 2654435761u
                       ^ (unsigned)(sub * 8 + t) * 40503u ^ (unsigned)r;
            va[t] = make_float4(u & 2 ? 1.f : -1.f, u & 4 ? 1.f : -1.f,
                                u & 8 ? 1.f : -1.f, u & 16 ? 1.f : -1.f);
        }
    }

    // ---- conns in registers (wave-uniform scalars via shfl+readfirstlane) ----
    int c_l = (lane < NB) ? connections[(size_t)r * NB + lane] : 0;
    int cb[NB];
    #pragma unroll
    for (int b = 0; b < NB; ++b)
        cb[b] = __builtin_amdgcn_readfirstlane(__shfl(c_l, b));

    unsigned qmask = 0, kmask = 0, pmask = 0;
    #pragma unroll
    for (int b = 0; b < NB; ++b) {
        qmask |= (unsigned)(cb[b] < 256) << b;
        kmask |= (unsigned)(cb[b] >= 256 && cb[b] < 512) << b;
        pmask |= (unsigned)(cb[b] >= 512) << b;
    }
    const int qb = __popc(qmask);
    const int kb = __popc(kmask);
    const bool fast = (pmask == 0);

    // ---- stage packed tokens (4KB, coalesced, L2-hot) ----
    ((int4*)tokT)[tid] = ((const int4*)tokP)[tid];
    __syncthreads();   // BAR1: tokT visible

    // ---- phase1: class build, own half ii = sub*64+lane ----
    const int ii = sub * 64 + lane;
    unsigned qcls = 0;                     // fast: query class | fb: sig(aq)
    if (fast) {
        unsigned qc = 0, kc = 0;
        int qn = 0, kn = 0;
        #pragma unroll
        for (int b = 0; b < NB; ++b) {
            int c = cb[b];
            if (c < 256) {
                qc |= ((tokT[TW(c) * S + ii] >> TP(c)) & 1u) << qn;
                ++qn;
            } else {
                int c2 = c - 256;
                kc |= ((tokT[TW(c2) * S + ii] >> TP(c2)) & 1u) << kn;
                ++kn;
            }
        }
        akT[rs][ii] = (unsigned short)kc;
        qcls = qc;
    } else {
        unsigned aq = 0, ak = 0, ap = 0;
        #pragma unroll
        for (int b = 0; b < NB; ++b) {
            int c = cb[b];
            if (c < 256) {
                aq |= ((tokT[TW(c) * S + ii] >> TP(c)) & 1u) << b;
            } else if (c < 512) {
                int c2 = c - 256;
                ak |= ((tokT[TW(c2) * S + ii] >> TP(c2)) & 1u) << b;
            } else {
                ap |= (((unsigned)ii >> (c - 512)) & 1u) << b;
            }
        }
        akT[rs][ii] = (unsigned short)sig(ak);
        apt[rs][ii] = (unsigned short)sig(ap);
        aqs[rs][ii] = (unsigned short)sig(aq);
        qcls = sig(aq);
    }

    // ---- consume own tiles -> sigma byte-table half ----
    #pragma unroll
    for (int t = 0; t < 8; ++t) {
        float4 v = va[t & 3];
        if (t + 4 < 8) {
            if (LOADS) {
                va[t & 3] = mp[lane + 64 * (sub * 8 + t + 4)];
            } else {
                unsigned u = (unsigned)lane * 2654435761u
                           ^ (unsigned)(sub * 8 + t + 4) * 40503u ^ (unsigned)r;
                va[t & 3] = make_float4(u & 2 ? 1.f : -1.f, u & 4 ? 1.f : -1.f,
                                        u & 8 ? 1.f : -1.f, u & 16 ? 1.f : -1.f);
            }
        }
        unsigned w = (unsigned)(v.x > 0.f)
                   | ((unsigned)(v.y > 0.f) << 8)
                   | ((unsigned)(v.z > 0.f) << 16)
                   | ((unsigned)(v.w > 0.f) << 24);
        *(unsigned*)&bt[sig(4u * (unsigned)(lane + 64 * (sub * 8 + t)))] = w;
    }
    __syncthreads();   // BAR2: bytetab + class tables complete

    unsigned long long rpart = 0;          // this wave's 64 result bits
    unsigned long long Wfull = 0;
    unsigned long long Vreg  = 0;          // formA sub1 carry
    unsigned Creg = 0;                     // formB sub1 carry
    unsigned acc_fb = 0;                   // fb sub1 carry

    if (fast) {
        // ---- phase2: repack own 32 words of the lane-distributed bit-LUT
        //      gbit = (Lcls << SBITS) | Scls; lane w holds bits [64w,64w+64)
        const bool formA = (qb <= 6);
        const int SBITS  = formA ? qb : kb;
        unsigned apl = 0, aul = 0;
        {
            int scnt = 0, lcnt = 0;
            #pragma unroll
            for (int b = 0; b < NB; ++b) {
                int c = cb[b];
                bool isS = formA ? (c < 256) : (c >= 256);
                if (isS) {
                    apl |= (((unsigned)lane >> scnt) & 1u) << b;
                    ++scnt;
                } else {
                    int p = SBITS + lcnt;
                    if (p < 6) apl |= (((unsigned)lane >> p) & 1u) << b;
                    else       aul |= (((unsigned)lane >> (p - 6)) & 1u) << b;
                    ++lcnt;
                }
            }
        }
        const unsigned spl  = sig(apl);
        const unsigned saul = sig(aul);
        unsigned Wlo = 0, Whi = 0;
        #pragma unroll 8
        for (int k = 0; k < 32; ++k) {
            int it = sub * 32 + k;
            unsigned sau  = (unsigned)__builtin_amdgcn_readlane((int)saul, it);
            unsigned bitv = bt[sau ^ spl] & 1u;   // sign at gbit = it*64+lane
            unsigned long long Bm = __ballot(bitv != 0u);
            Wlo = (lane == it) ? (unsigned)Bm : Wlo;
            Whi = (lane == it) ? (unsigned)(Bm >> 32) : Whi;
        }
        if ((lane >> 5) == sub)
            wsh[rs][lane] = ((unsigned long long)Whi << 32) | Wlo;
    } else {
        // ---- phase2: fb sweep own j-range (lanes = queries) ----
        if (sub == 0) {
            const unsigned aqv0 = qcls;                 // query i = lane
            const unsigned aqvU = aqs[rs][64 + lane];   // query i = 64+lane
            unsigned acc0 = 0, accP = 0;
            for (int s8 = 0; s8 < 8; ++s8) {            // j = 0..63
                uint4 uk = *(const uint4*)&akT[rs][s8 * 8];
                #pragma unroll
                for (int t = 0; t < 8; ++t) {
                    int j = s8 * 8 + t;
                    unsigned w = ((const unsigned*)&uk)[t >> 1];
                    unsigned akv = (w >> ((t & 1) * 16)) & 0xffffu;
                    int d0 = lane - j;                  // <0 -> masked out
                    unsigned v0 = bt[aqv0 ^ akv ^ (unsigned)apt[rs][d0 & 127]] & 1u;
                    acc0 ^= (d0 >= 0) ? v0 : 0u;
                    int d1 = lane + 64 - j;             // in [1,127]: active
                    unsigned v1 = bt[aqvU ^ akv ^ (unsigned)apt[rs][d1]] & 1u;
                    accP ^= v1;
                }
            }
            rpart = __ballot(acc0 != 0u);
            unsigned long long up = __ballot(accP != 0u);
            if (lane == 0) fbu[rs] = up;
        } else {
            const unsigned aqv1 = qcls;                 // query i = 64+lane
            unsigned acc1 = 0;
            for (int s8 = 8; s8 < 16; ++s8) {           // j = 64..127
                uint4 uk = *(const uint4*)&akT[rs][s8 * 8];
                #pragma unroll
                for (int t = 0; t < 8; ++t) {
                    int j = s8 * 8 + t;
                    unsigned w = ((const unsigned*)&uk)[t >> 1];
                    unsigned akv = (w >> ((t & 1) * 16)) & 0xffffu;
                    int d1 = lane + 64 - j;             // <0 -> masked out
                    unsigned v1 = bt[aqv1 ^ akv ^ (unsigned)apt[rs][d1 & 127]] & 1u;
                    acc1 ^= (d1 >= 0) ? v1 : 0u;
                }
            }
            acc_fb = acc1;
        }
    }
    __syncthreads();   // BAR3: wsh halves / fbu visible

    if (fast) {
        Wfull = wsh[rs][lane];             // full 64-word LUT, word per lane
        const bool formA = (qb <= 6);
        if (formA) {
            // prefix-XOR over own key half; lane j = key sub*64+j.
            unsigned kcls = akT[rs][ii];
            unsigned g0 = kcls << qb;
            unsigned long long V = __shfl(Wfull, (int)(g0 >> 6)) >> (g0 & 63u);
            #pragma unroll
            for (int d = 1; d < 64; d <<= 1) {
                unsigned long long u = __shfl_up(V, (unsigned)d);
                V ^= (lane >= d) ? u : 0ull;
            }
            if (sub == 0) {
                rpart = __ballot(((V >> qcls) & 1ull) != 0ull);
                unsigned long long Ab = __shfl(V, 63);
                if (lane == 0) baseS[rs] = Ab;
            } else {
                Vreg = V;                  // fold carry after BAR4
            }
        } else {
            // kb <= 5: one-hot key-class prefix parity word
            unsigned kcls = akT[rs][ii];
            unsigned C = 1u << kcls;
            #pragma unroll
            for (int d = 1; d < 64; d <<= 1) {
                unsigned u = __shfl_up(C, (unsigned)d);
                C ^= (lane >= d) ? u : 0u;
            }
            if (sub == 0) {
                unsigned g0a = qcls << kb;
                unsigned W0 = (unsigned)(__shfl(Wfull, (int)(g0a >> 6)) >> (g0a & 63u));
                rpart = __ballot((__popc(W0 & C) & 1) != 0);
                unsigned Cb = __shfl(C, 63);
                if (lane == 0) baseS[rs] = (unsigned long long)Cb;
            } else {
                Creg = C;
            }
        }
    } else if (sub == 1) {
        // fold A's always-active partial into the upper-query accumulators
        unsigned long long up = fbu[rs];
        acc_fb ^= (unsigned)((up >> lane) & 1ull);
        rpart = __ballot(acc_fb != 0u);
    }
    __syncthreads();   // BAR4: baseS visible

    if (fast && sub == 1) {
        const bool formA = (qb <= 6);
        if (formA) {
            unsigned long long V1 = Vreg ^ baseS[rs];
            rpart = __ballot(((V1 >> qcls) & 1ull) != 0ull);
        } else {
            unsigned C1 = Creg ^ (unsigned)baseS[rs];
            unsigned g0b = qcls << kb;
            unsigned W1 = (unsigned)(__shfl(Wfull, (int)(g0b >> 6)) >> (g0b & 63u));
            rpart = __ballot((__popc(W1 & C1) & 1) != 0);
        }
    }

    if (lane == 0) pres[(size_t)r * 2 + sub] = rpart;
}

__global__ __launch_bounds__(128) void vote_kernel(
    const unsigned long long* __restrict__ pres,  // [4096][2]
    int* __restrict__ out)                        // [S,B]
{
    const int n = blockIdx.x;              // 0..255
    const int i = threadIdx.x;             // 0..127
    const int w = i >> 6, b = i & 63;
    int tot = 0;
    #pragma unroll
    for (int h = 0; h < H; ++h)
        tot += (int)((pres[(size_t)(h * 256 + n) * 2 + w] >> b) & 1ull);
    out[i * B + n] = (tot > (H / 2)) ? 1 : 0;
}

extern "C" void kernel_launch(void* const* d_in, const int* in_sizes, int n_in,
                              void* d_out, int out_size, void* d_ws, size_t ws_size,
                              hipStream_t stream) {
    const int*   tokens      = (const int*)d_in[0];
    const float* memory      = (const float*)d_in[1];
    const int*   connections = (const int*)d_in[2];
    int*         out         = (int*)d_out;
    unsigned long long* pres  = (unsigned long long*)d_ws;              // 64 KB @ 0
    unsigned*           tokP  = (unsigned*)((char*)d_ws + (64u << 10)); // 4 KB @ 64K
    unsigned long long* pres2 = (unsigned long long*)((char*)d_ws + (128u << 10)); // scratch
    (void)in_sizes; (void)n_in; (void)out_size; (void)ws_size;

    pack_kernel<<<8, 256, 0, stream>>>(tokens, tokP);
    softram_kernel<1><<<2048, 256, 0, stream>>>(tokP, memory, connections, pres);
    vote_kernel<<<B, 128, 0, stream>>>(pres, out);
    // ---- diagnostic: compute-only replica to scratch (timing delta = C) ----
    softram_kernel<0><<<2048, 256, 0, stream>>>(tokP, memory, connections, pres2);
}

// Round 9
// 111.587 us; speedup vs baseline: 1.1164x; 1.1164x over previous
//
#include <hip/hip_runtime.h>

// SoftRAM attention: S=128, B=256 bits, H=16 heads, NB=12 bits/neuron, PB=7.
// addr(i,j,h,n) = aq_i | ak_j | ap_{i-j}, disjoint bit groups per (h,n).
//
// R17: cross-row pipelining. R16's ablation: compute-only C=16us, with-loads
// 34.5us -> stream (18.5us) and compute SERIALIZE. Cause: __syncthreads
// forces s_waitcnt vmcnt(0) (barrier drain), killing any prefetch, and each
// row's compute depends on its own stream. Fix (T3/T4 pattern):
//  - each block runs TWO sequential row-generations (grid 1024 x 4 waves;
//    per-gen structure = verified R15 2-waves-per-row math, unchanged);
//  - BOTH generations' 16KB prefetched to registers at kernel top
//    (16 x b128 in flight per wave; cl/tokP loads issued first so their
//    waits don't drain the prefetch);
//  - raw s_barrier + s_waitcnt lgkmcnt(0) ONLY (no vmcnt at barriers):
//    gen1's loads fly beneath gen0's whole repack+sweep;
//  - LDS tables single-buffered, reuse barrier-ordered (phase4 reads no
//    shared tables; gen1 writes happen after the barrier following gen0's
//    last table read). launch_bounds(256,4) -> 128-VGPR budget.

#define S 128
#define B 256
#define H 16
#define NB 12

__device__ __forceinline__ unsigned sig(unsigned x) {
    return x ^ ((x >> 3) & 0x70u) ^ ((x >> 6) & 0x70u);
}

// token bit c lives at packed word TW(c), bit TP(c)
#define TW(c) ((((c) & 3) << 1) + ((c) >> 7))
#define TP(c) (((c) >> 2) & 31)

// barrier WITHOUT vmcnt drain: commit own LDS writes, sync, pin order.
#define LGKM_BAR() do { \
    asm volatile("s_waitcnt lgkmcnt(0)" ::: "memory"); \
    __builtin_amdgcn_s_barrier(); \
    __builtin_amdgcn_sched_barrier(0); \
} while (0)

__global__ __launch_bounds__(256) void pack_kernel(
    const int* __restrict__ tokens,        // [S,B] 0/1
    unsigned* __restrict__ tokP)           // [8][S] packed
{
    const int wid  = threadIdx.x >> 6;
    const int lane = threadIdx.x & 63;
    const int4* tp = (const int4*)tokens;
    #pragma unroll
    for (int r = 0; r < 4; ++r) {
        int i = blockIdx.x * 16 + wid * 4 + r;
        int4 x = tp[i * 64 + lane];        // coalesced: full row of 256 ints
        unsigned long long B0 = __ballot((x.x & 1) != 0);  // bit l = tok[4l+0]
        unsigned long long B1 = __ballot((x.y & 1) != 0);
        unsigned long long B2 = __ballot((x.z & 1) != 0);
        unsigned long long B3 = __ballot((x.w & 1) != 0);
        int c = lane >> 1;                 // word index = comp*2 + half
        unsigned long long s01 = (c & 1) ? B1 : B0;
        unsigned long long s23 = (c & 1) ? B3 : B2;
        unsigned long long s   = (c & 2) ? s23 : s01;
        unsigned word = (lane & 1) ? (unsigned)(s >> 32) : (unsigned)s;
        if (lane < 8) tokP[lane * 128 + i] = word;
    }
}

__global__ __launch_bounds__(256, 4) void softram_kernel(
    const unsigned* __restrict__ tokP,     // [8][S] packed tokens
    const float* __restrict__ memory,      // [H,B,4096]
    const int* __restrict__ connections,   // [H,B,NB]
    unsigned long long* __restrict__ pres) // [4096][2] result bits per row
{
    const int tid  = threadIdx.x;
    const int wid  = tid >> 6;
    const int rs   = wid >> 1;             // row slot in block (0/1)
    const int sub  = wid & 1;              // half (0: lo, 1: hi)
    const int lane = tid & 63;
    const int r0   = blockIdx.x * 4 + rs;       // generation-0 row
    const int r1   = blockIdx.x * 4 + 2 + rs;   // generation-1 row
    const int ii   = sub * 64 + lane;

    __shared__ __align__(16) unsigned char      bytetab[2][4096]; // 8 KB
    __shared__ __align__(16) unsigned int       tokT[8 * S];      // 4 KB
    __shared__ __align__(16) unsigned short     akT[2][S];        // key cls / sig(ak)
    __shared__ __align__(16) unsigned short     apt[2][S];        // sig(ap) (fb)
    __shared__ __align__(16) unsigned short     aqs[2][S];        // sig(aq) (fb)
    __shared__ __align__(16) unsigned long long wsh[2][64];       // 1 KB bit-LUT
    __shared__ unsigned long long baseS[2];                       // prefix carry
    __shared__ unsigned long long fbu[2];                         // fb upper part

    // ---- small loads FIRST (so their waits don't drain the prefetch) ----
    int cl0 = (lane < NB) ? connections[(size_t)r0 * NB + lane] : 0;
    int cl1 = (lane < NB) ? connections[(size_t)r1 * NB + lane] : 0;
    int4 tk = ((const int4*)tokP)[tid];

    // ---- full prefetch: both generations' half-rows (16 x b128 in flight) ----
    const float4* mp0 = (const float4*)(memory + ((size_t)r0 << 12));
    const float4* mp1 = (const float4*)(memory + ((size_t)r1 << 12));
    float4 va0[8], va1[8];
    #pragma unroll
    for (int t = 0; t < 8; ++t) va0[t] = mp0[lane + 64 * (sub * 8 + t)];
    #pragma unroll
    for (int t = 0; t < 8; ++t) va1[t] = mp1[lane + 64 * (sub * 8 + t)];

    ((int4*)tokT)[tid] = tk;               // waits only for tk (issued first)
    LGKM_BAR();   // BAR1: tokT visible; bulk prefetch stays in flight

    auto do_gen = [&](int r, float4 (&va)[8], int c_l) {
        unsigned char* __restrict__ bt = bytetab[rs];

        // ---- masks (wave-uniform scalars) ----
        int cb[NB];
        #pragma unroll
        for (int b = 0; b < NB; ++b)
            cb[b] = __builtin_amdgcn_readfirstlane(__shfl(c_l, b));
        unsigned qmask = 0, kmask = 0, pmask = 0;
        #pragma unroll
        for (int b = 0; b < NB; ++b) {
            qmask |= (unsigned)(cb[b] < 256) << b;
            kmask |= (unsigned)(cb[b] >= 256 && cb[b] < 512) << b;
            pmask |= (unsigned)(cb[b] >= 512) << b;
        }
        const int qb = __popc(qmask);
        const int kb = __popc(kmask);
        const bool fast = (pmask == 0);

        // ---- phase1: class build (LDS-only; overlaps this gen's drain) ----
        unsigned qcls = 0;                 // fast: query class | fb: sig(aq)
        if (fast) {
            unsigned qc = 0, kc = 0;
            int qn = 0, kn = 0;
            #pragma unroll
            for (int b = 0; b < NB; ++b) {
                int c = cb[b];
                if (c < 256) {
                    qc |= ((tokT[TW(c) * S + ii] >> TP(c)) & 1u) << qn;
                    ++qn;
                } else {
                    int c2 = c - 256;
                    kc |= ((tokT[TW(c2) * S + ii] >> TP(c2)) & 1u) << kn;
                    ++kn;
                }
            }
            akT[rs][ii] = (unsigned short)kc;
            qcls = qc;
        } else {
            unsigned aq = 0, ak = 0, ap = 0;
            #pragma unroll
            for (int b = 0; b < NB; ++b) {
                int c = cb[b];
                if (c < 256) {
                    aq |= ((tokT[TW(c) * S + ii] >> TP(c)) & 1u) << b;
                } else if (c < 512) {
                    int c2 = c - 256;
                    ak |= ((tokT[TW(c2) * S + ii] >> TP(c2)) & 1u) << b;
                } else {
                    ap |= (((unsigned)ii >> (c - 512)) & 1u) << b;
                }
            }
            akT[rs][ii] = (unsigned short)sig(ak);
            apt[rs][ii] = (unsigned short)sig(ap);
            aqs[rs][ii] = (unsigned short)sig(aq);
            qcls = sig(aq);
        }

        // ---- consume prefetched tiles -> sigma byte-table half ----
        #pragma unroll
        for (int t = 0; t < 8; ++t) {
            float4 v = va[t];              // compiler: counted vmcnt wait
            unsigned w = (unsigned)(v.x > 0.f)
                       | ((unsigned)(v.y > 0.f) << 8)
                       | ((unsigned)(v.z > 0.f) << 16)
                       | ((unsigned)(v.w > 0.f) << 24);
            *(unsigned*)&bt[sig(4u * (unsigned)(lane + 64 * (sub * 8 + t)))] = w;
        }
        LGKM_BAR();   // BAR-a: bytetab + class tables complete

        unsigned long long rpart = 0;
        unsigned long long Wfull = 0;
        unsigned long long Vreg  = 0;      // formA sub1 carry
        unsigned Creg = 0;                 // formB sub1 carry
        unsigned acc_fb = 0;               // fb sub1 carry

        if (fast) {
            // ---- phase2: repack own 32 words of the bit-LUT ----
            const bool formA = (qb <= 6);
            const int SBITS  = formA ? qb : kb;
            unsigned apl = 0, aul = 0;
            {
                int scnt = 0, lcnt = 0;
                #pragma unroll
                for (int b = 0; b < NB; ++b) {
                    int c = cb[b];
                    bool isS = formA ? (c < 256) : (c >= 256);
                    if (isS) {
                        apl |= (((unsigned)lane >> scnt) & 1u) << b;
                        ++scnt;
                    } else {
                        int p = SBITS + lcnt;
                        if (p < 6) apl |= (((unsigned)lane >> p) & 1u) << b;
                        else       aul |= (((unsigned)lane >> (p - 6)) & 1u) << b;
                        ++lcnt;
                    }
                }
            }
            const unsigned spl  = sig(apl);
            const unsigned saul = sig(aul);
            unsigned Wlo = 0, Whi = 0;
            #pragma unroll 8
            for (int k = 0; k < 32; ++k) {
                int it = sub * 32 + k;
                unsigned sau  = (unsigned)__builtin_amdgcn_readlane((int)saul, it);
                unsigned bitv = bt[sau ^ spl] & 1u;   // sign at gbit=it*64+lane
                unsigned long long Bm = __ballot(bitv != 0u);
                Wlo = (lane == it) ? (unsigned)Bm : Wlo;
                Whi = (lane == it) ? (unsigned)(Bm >> 32) : Whi;
            }
            if ((lane >> 5) == sub)
                wsh[rs][lane] = ((unsigned long long)Whi << 32) | Wlo;
        } else {
            // ---- phase2: fb sweep own j-range (lanes = queries) ----
            if (sub == 0) {
                const unsigned aqv0 = qcls;                 // query i = lane
                const unsigned aqvU = aqs[rs][64 + lane];   // query i = 64+lane
                unsigned acc0 = 0, accP = 0;
                for (int s8 = 0; s8 < 8; ++s8) {            // j = 0..63
                    uint4 uk = *(const uint4*)&akT[rs][s8 * 8];
                    #pragma unroll
                    for (int t = 0; t < 8; ++t) {
                        int j = s8 * 8 + t;
                        unsigned w = ((const unsigned*)&uk)[t >> 1];
                        unsigned akv = (w >> ((t & 1) * 16)) & 0xffffu;
                        int d0 = lane - j;                  // <0 -> masked out
                        unsigned v0 = bt[aqv0 ^ akv ^ (unsigned)apt[rs][d0 & 127]] & 1u;
                        acc0 ^= (d0 >= 0) ? v0 : 0u;
                        int d1 = lane + 64 - j;             // in [1,127]: active
                        unsigned v1 = bt[aqvU ^ akv ^ (unsigned)apt[rs][d1]] & 1u;
                        accP ^= v1;
                    }
                }
                rpart = __ballot(acc0 != 0u);
                unsigned long long up = __ballot(accP != 0u);
                if (lane == 0) fbu[rs] = up;
            } else {
                const unsigned aqv1 = qcls;                 // query i = 64+lane
                unsigned acc1 = 0;
                for (int s8 = 8; s8 < 16; ++s8) {           // j = 64..127
                    uint4 uk = *(const uint4*)&akT[rs][s8 * 8];
                    #pragma unroll
                    for (int t = 0; t < 8; ++t) {
                        int j = s8 * 8 + t;
                        unsigned w = ((const unsigned*)&uk)[t >> 1];
                        unsigned akv = (w >> ((t & 1) * 16)) & 0xffffu;
                        int d1 = lane + 64 - j;             // <0 -> masked out
                        unsigned v1 = bt[aqv1 ^ akv ^ (unsigned)apt[rs][d1 & 127]] & 1u;
                        acc1 ^= (d1 >= 0) ? v1 : 0u;
                    }
                }
                acc_fb = acc1;
            }
        }
        LGKM_BAR();   // BAR-b: wsh halves / fbu visible

        if (fast) {
            Wfull = wsh[rs][lane];         // full 64-word LUT, word per lane
            const bool formA = (qb <= 6);
            if (formA) {
                // prefix-XOR over own key half; lane j = key sub*64+j.
                unsigned kcls = akT[rs][ii];
                unsigned g0 = kcls << qb;
                unsigned long long V = __shfl(Wfull, (int)(g0 >> 6)) >> (g0 & 63u);
                #pragma unroll
                for (int d = 1; d < 64; d <<= 1) {
                    unsigned long long u = __shfl_up(V, (unsigned)d);
                    V ^= (lane >= d) ? u : 0ull;
                }
                if (sub == 0) {
                    rpart = __ballot(((V >> qcls) & 1ull) != 0ull);
                    unsigned long long Ab = __shfl(V, 63);
                    if (lane == 0) baseS[rs] = Ab;
                } else {
                    Vreg = V;              // fold carry after BAR-c
                }
            } else {
                // kb <= 5: one-hot key-class prefix parity word
                unsigned kcls = akT[rs][ii];
                unsigned C = 1u << kcls;
                #pragma unroll
                for (int d = 1; d < 64; d <<= 1) {
                    unsigned u = __shfl_up(C, (unsigned)d);
                    C ^= (lane >= d) ? u : 0u;
                }
                if (sub == 0) {
                    unsigned g0a = qcls << kb;
                    unsigned W0 = (unsigned)(__shfl(Wfull, (int)(g0a >> 6)) >> (g0a & 63u));
                    rpart = __ballot((__popc(W0 & C) & 1) != 0);
                    unsigned Cb = __shfl(C, 63);
                    if (lane == 0) baseS[rs] = (unsigned long long)Cb;
                } else {
                    Creg = C;
                }
            }
        } else if (sub == 1) {
            // fold sub0's always-active partial into upper-query accumulators
            unsigned long long up = fbu[rs];
            acc_fb ^= (unsigned)((up >> lane) & 1ull);
            rpart = __ballot(acc_fb != 0u);
        }
        LGKM_BAR();   // BAR-c: baseS visible (phase4 reads NO shared tables)

        if (fast && sub == 1) {
            const bool formA = (qb <= 6);
            if (formA) {
                unsigned long long V1 = Vreg ^ baseS[rs];
                rpart = __ballot(((V1 >> qcls) & 1ull) != 0ull);
            } else {
                unsigned C1 = Creg ^ (unsigned)baseS[rs];
                unsigned g0b = qcls << kb;
                unsigned W1 = (unsigned)(__shfl(Wfull, (int)(g0b >> 6)) >> (g0b & 63u));
                rpart = __ballot((__popc(W1 & C1) & 1) != 0);
            }
        }

        if (lane == 0) pres[(size_t)r * 2 + sub] = rpart;
    };

    do_gen(r0, va0, cl0);   // gen1's 8KB stays in flight under gen0 compute
    do_gen(r1, va1, cl1);
}

__global__ __launch_bounds__(128) void vote_kernel(
    const unsigned long long* __restrict__ pres,  // [4096][2]
    int* __restrict__ out)                        // [S,B]
{
    const int n = blockIdx.x;              // 0..255
    const int i = threadIdx.x;             // 0..127
    const int w = i >> 6, b = i & 63;
    int tot = 0;
    #pragma unroll
    for (int h = 0; h < H; ++h)
        tot += (int)((pres[(size_t)(h * 256 + n) * 2 + w] >> b) & 1ull);
    out[i * B + n] = (tot > (H / 2)) ? 1 : 0;
}

extern "C" void kernel_launch(void* const* d_in, const int* in_sizes, int n_in,
                              void* d_out, int out_size, void* d_ws, size_t ws_size,
                              hipStream_t stream) {
    const int*   tokens      = (const int*)d_in[0];
    const float* memory      = (const float*)d_in[1];
    const int*   connections = (const int*)d_in[2];
    int*         out         = (int*)d_out;
    unsigned long long* pres = (unsigned long long*)d_ws;              // 64 KB @ 0
    unsigned*           tokP = (unsigned*)((char*)d_ws + (64u << 10)); // 4 KB @ 64K
    (void)in_sizes; (void)n_in; (void)out_size; (void)ws_size;

    pack_kernel<<<8, 256, 0, stream>>>(tokens, tokP);
    // 4096 rows, 2 row-slots x 2 generations per block -> 1024 blocks
    softram_kernel<<<1024, 256, 0, stream>>>(tokP, memory, connections, pres);
    vote_kernel<<<B, 128, 0, stream>>>(pres, out);
}

// Round 10
// 107.144 us; speedup vs baseline: 1.1627x; 1.0415x over previous
//
#include <hip/hip_runtime.h>

// SoftRAM attention: S=128, B=256 bits, H=16 heads, NB=12 bits/neuron, PB=7.
// addr(i,j,h,n) = aq_i | ak_j | ap_{i-j}, disjoint bit groups per (h,n).
//
// R18: producer/consumer wave specialization. Ledger: stream 18.5us exposed +
// compute 16us SERIALIZE (R16 ablation); intra-wave overlap attempts null
// (R12) or occupancy-negative (R17). The only work that can run under the
// stream is OTHER rows' compute -> decouple via specialized waves (the
// CDNA-guide-recommended path past the barrier-drain wall).
//   grid 2048 x 256thr (4 waves), 2 rows/block:
//   - waves 0,1 (producers): stream row s=wid (16KB, 4-deep reg ring, ~30
//     VGPR, no conns/tokens needed) -> sigma byte-table -> lgkmcnt drain ->
//     flag[s]=1. Never touch LDS tables.
//   - waves 2,3 (consumers): class build from tokT (overlaps stream) ->
//     volatile poll flag[s] -> repack + sweep = R11-verified full-row wave
//     body. Never wait on vmcnt.
//   One __syncthreads total (tokT staging, before any bulk loads). LDS
//   ~13.3KB, VGPR target <=64 -> 8 blocks/CU = 32 waves/CU, phases decoupled:
//   early rows' compute hides under later rows' stream.

#define S 128
#define B 256
#define H 16
#define NB 12

__device__ __forceinline__ unsigned sig(unsigned x) {
    return x ^ ((x >> 3) & 0x70u) ^ ((x >> 6) & 0x70u);
}

// token bit c lives at packed word TW(c), bit TP(c)
#define TW(c) ((((c) & 3) << 1) + ((c) >> 7))
#define TP(c) (((c) >> 2) & 31)

__global__ __launch_bounds__(256) void pack_kernel(
    const int* __restrict__ tokens,        // [S,B] 0/1
    unsigned* __restrict__ tokP)           // [8][S] packed
{
    const int wid  = threadIdx.x >> 6;
    const int lane = threadIdx.x & 63;
    const int4* tp = (const int4*)tokens;
    #pragma unroll
    for (int r = 0; r < 4; ++r) {
        int i = blockIdx.x * 16 + wid * 4 + r;
        int4 x = tp[i * 64 + lane];        // coalesced: full row of 256 ints
        unsigned long long B0 = __ballot((x.x & 1) != 0);  // bit l = tok[4l+0]
        unsigned long long B1 = __ballot((x.y & 1) != 0);
        unsigned long long B2 = __ballot((x.z & 1) != 0);
        unsigned long long B3 = __ballot((x.w & 1) != 0);
        int c = lane >> 1;                 // word index = comp*2 + half
        unsigned long long s01 = (c & 1) ? B1 : B0;
        unsigned long long s23 = (c & 1) ? B3 : B2;
        unsigned long long s   = (c & 2) ? s23 : s01;
        unsigned word = (lane & 1) ? (unsigned)(s >> 32) : (unsigned)s;
        if (lane < 8) tokP[lane * 128 + i] = word;
    }
}

__global__ __launch_bounds__(256, 8) void softram_kernel(
    const unsigned* __restrict__ tokP,     // [8][S] packed tokens
    const float* __restrict__ memory,      // [H,B,4096]
    const int* __restrict__ connections,   // [H,B,NB]
    unsigned long long* __restrict__ pres) // [4096][2] result bits per row
{
    const int tid  = threadIdx.x;
    const int wid  = tid >> 6;
    const int lane = tid & 63;
    const bool producer = (wid < 2);
    const int s = producer ? wid : (wid - 2);   // row slot (0/1)
    const int r = blockIdx.x * 2 + s;           // row = h*256+n

    __shared__ __align__(16) unsigned char  bytetab[2][4096]; // 8 KB signs
    __shared__ __align__(16) unsigned int   tokT[8 * S];      // 4 KB packed
    __shared__ __align__(16) unsigned short akT[2][S];        // key cls / sig(ak)
    __shared__ __align__(16) unsigned short apt[2][S];        // sig(ap) (fb)
    __shared__ int flag[2];                                   // row-ready

    // ---- pre-barrier loads: conns (consumers only) + tokT stage ----
    int c_l = 0;
    if (!producer && lane < NB) c_l = connections[(size_t)r * NB + lane];
    ((int4*)tokT)[tid] = ((const int4*)tokP)[tid];
    if (tid < 2) flag[tid] = 0;
    __syncthreads();   // the ONLY barrier: drains tokT/conns loads only

    unsigned char* __restrict__ bt = bytetab[s];

    if (producer) {
        // ============== producer: stream row -> sigma byte-table ==============
        const float4* mp = (const float4*)(memory + ((size_t)r << 12));
        float4 va[4];
        #pragma unroll
        for (int t = 0; t < 4; ++t) va[t] = mp[lane + 64 * t];
        #pragma unroll
        for (int t = 0; t < 16; ++t) {
            float4 v = va[t & 3];
            if (t + 4 < 16) va[t & 3] = mp[lane + 64 * (t + 4)];
            unsigned w = (unsigned)(v.x > 0.f)
                       | ((unsigned)(v.y > 0.f) << 8)
                       | ((unsigned)(v.z > 0.f) << 16)
                       | ((unsigned)(v.w > 0.f) << 24);
            *(unsigned*)&bt[sig(4u * (unsigned)(lane + 64 * t))] = w;
        }
        asm volatile("s_waitcnt lgkmcnt(0)" ::: "memory");  // commit bt writes
        if (lane == 0) *(volatile int*)&flag[s] = 1;
        return;
    }

    // ================== consumer: R11-verified full-row body ==================
    int cb[NB];
    #pragma unroll
    for (int b = 0; b < NB; ++b)
        cb[b] = __builtin_amdgcn_readfirstlane(__shfl(c_l, b));

    unsigned qmask = 0, kmask = 0, pmask = 0;
    #pragma unroll
    for (int b = 0; b < NB; ++b) {
        qmask |= (unsigned)(cb[b] < 256) << b;
        kmask |= (unsigned)(cb[b] >= 256 && cb[b] < 512) << b;
        pmask |= (unsigned)(cb[b] >= 512) << b;
    }
    const int qb = __popc(qmask);
    const int kb = __popc(kmask);
    const bool fast = (pmask == 0);

    // ---- class build (tokT only; overlaps the producer's stream) ----
    unsigned qclsA = 0, qclsB = 0;     // fast: query classes | fb: sig(aq)
    if (fast) {
        #pragma unroll
        for (int e = 0; e < 2; ++e) {
            int ii = lane + 64 * e;
            unsigned qc = 0, kc = 0;
            int qn = 0, kn = 0;
            #pragma unroll
            for (int b = 0; b < NB; ++b) {
                int c = cb[b];
                if (c < 256) {
                    qc |= ((tokT[TW(c) * S + ii] >> TP(c)) & 1u) << qn;
                    ++qn;
                } else {
                    int c2 = c - 256;
                    kc |= ((tokT[TW(c2) * S + ii] >> TP(c2)) & 1u) << kn;
                    ++kn;
                }
            }
            akT[s][ii] = (unsigned short)kc;
            if (e == 0) qclsA = qc; else qclsB = qc;
        }
    } else {
        #pragma unroll
        for (int e = 0; e < 2; ++e) {
            int ii = lane + 64 * e;
            unsigned aq = 0, ak = 0, ap = 0;
            #pragma unroll
            for (int b = 0; b < NB; ++b) {
                int c = cb[b];
                if (c < 256) {
                    aq |= ((tokT[TW(c) * S + ii] >> TP(c)) & 1u) << b;
                } else if (c < 512) {
                    int c2 = c - 256;
                    ak |= ((tokT[TW(c2) * S + ii] >> TP(c2)) & 1u) << b;
                } else {
                    ap |= (((unsigned)ii >> (c - 512)) & 1u) << b;
                }
            }
            akT[s][ii] = (unsigned short)sig(ak);
            apt[s][ii] = (unsigned short)sig(ap);
            if (e == 0) qclsA = sig(aq); else qclsB = sig(aq);
        }
    }

    // ---- wait for this row's byte table (wave-uniform spin) ----
    while (*(volatile int*)&flag[s] == 0) __builtin_amdgcn_s_sleep(2);
    asm volatile("" ::: "memory");         // no bt reads hoist above the poll
    __builtin_amdgcn_sched_barrier(0);

    unsigned long long rlo = 0, rhi = 0;

    if (fast) {
        // ---- repack to lane-distributed bit-LUT: lane w holds gbits
        //      [64w,64w+64), gbit = (Lcls << SBITS) | Scls ----
        const bool formA = (qb <= 6);      // bit-side = Q if qb<=6 else K
        const int SBITS  = formA ? qb : kb;
        unsigned apl = 0, aul = 0;
        {
            int scnt = 0, lcnt = 0;
            #pragma unroll
            for (int b = 0; b < NB; ++b) {
                int c = cb[b];
                bool isS = formA ? (c < 256) : (c >= 256);
                if (isS) {
                    apl |= (((unsigned)lane >> scnt) & 1u) << b;
                    ++scnt;
                } else {
                    int p = SBITS + lcnt;
                    if (p < 6) apl |= (((unsigned)lane >> p) & 1u) << b;
                    else       aul |= (((unsigned)lane >> (p - 6)) & 1u) << b;
                    ++lcnt;
                }
            }
        }
        const unsigned spl  = sig(apl);
        const unsigned saul = sig(aul);
        unsigned Wlo = 0, Whi = 0;
        #pragma unroll 8
        for (int it = 0; it < 64; ++it) {
            unsigned sau  = (unsigned)__builtin_amdgcn_readlane((int)saul, it);
            unsigned bitv = bt[sau ^ spl] & 1u;   // sign at gbit = it*64+lane
            unsigned long long Bm = __ballot(bitv != 0u);
#if __has_builtin(__builtin_amdgcn_writelane)
            Wlo = (unsigned)__builtin_amdgcn_writelane((int)(unsigned)Bm, it, (int)Wlo);
            Whi = (unsigned)__builtin_amdgcn_writelane((int)(unsigned)(Bm >> 32), it, (int)Whi);
#else
            Wlo = (lane == it) ? (unsigned)Bm : Wlo;
            Whi = (lane == it) ? (unsigned)(Bm >> 32) : Whi;
#endif
        }
        const unsigned long long Wfull = ((unsigned long long)Whi << 32) | Wlo;

        if (formA) {
            // lane-parallel prefix-XOR over keys; lane j = key j / key 64+j.
            unsigned kclsA = akT[s][lane];
            unsigned g0 = kclsA << qb;
            unsigned long long V = __shfl(Wfull, (int)(g0 >> 6)) >> (g0 & 63u);
            #pragma unroll
            for (int d = 1; d < 64; d <<= 1) {
                unsigned long long u = __shfl_up(V, (unsigned)d);
                V ^= (lane >= d) ? u : 0ull;
            }
            rlo = __ballot(((V >> qclsA) & 1ull) != 0ull);
            const unsigned long long Abase = __shfl(V, 63);

            unsigned kclsB = akT[s][64 + lane];
            unsigned g1 = kclsB << qb;
            unsigned long long V1 = __shfl(Wfull, (int)(g1 >> 6)) >> (g1 & 63u);
            #pragma unroll
            for (int d = 1; d < 64; d <<= 1) {
                unsigned long long u = __shfl_up(V1, (unsigned)d);
                V1 ^= (lane >= d) ? u : 0ull;
            }
            V1 ^= Abase;
            rhi = __ballot(((V1 >> qclsB) & 1ull) != 0ull);
        } else {
            // kb <= 5: prefix-XOR of one-hot key classes, then
            // r_i = parity(LUTrow[qcls_i] & prefix_i).
            unsigned kclsA = akT[s][lane];
            unsigned C = 1u << kclsA;
            #pragma unroll
            for (int d = 1; d < 64; d <<= 1) {
                unsigned u = __shfl_up(C, (unsigned)d);
                C ^= (lane >= d) ? u : 0u;
            }
            unsigned g0a = qclsA << kb;
            unsigned W0 = (unsigned)(__shfl(Wfull, (int)(g0a >> 6)) >> (g0a & 63u));
            rlo = __ballot((__popc(W0 & C) & 1) != 0);
            const unsigned Cbase = __shfl(C, 63);

            unsigned kclsB = akT[s][64 + lane];
            unsigned C1 = 1u << kclsB;
            #pragma unroll
            for (int d = 1; d < 64; d <<= 1) {
                unsigned u = __shfl_up(C1, (unsigned)d);
                C1 ^= (lane >= d) ? u : 0u;
            }
            C1 ^= Cbase;
            unsigned g0b = qclsB << kb;
            unsigned W1 = (unsigned)(__shfl(Wfull, (int)(g0b >> 6)) >> (g0b & 63u));
            rhi = __ballot((__popc(W1 & C1) & 1) != 0);
        }
    } else {
        // ---- P fallback: lanes = queries, arithmetic causal masks ----
        const unsigned aqv0 = qclsA, aqv1 = qclsB;
        unsigned acc0 = 0, acc1 = 0;
        for (int s8 = 0; s8 < 8; ++s8) {       // j = 0..63
            uint4 uk = *(const uint4*)&akT[s][s8 * 8];
            #pragma unroll
            for (int t = 0; t < 8; ++t) {
                int j = s8 * 8 + t;
                unsigned w = ((const unsigned*)&uk)[t >> 1];
                unsigned akv = (w >> ((t & 1) * 16)) & 0xffffu;
                int d0 = lane - j;             // <0 -> masked out
                unsigned v0 = bt[aqv0 ^ akv ^ (unsigned)apt[s][d0 & 127]] & 1u;
                acc0 ^= (d0 >= 0) ? v0 : 0u;
                int d1 = lane + 64 - j;        // in [1,127]: always active
                unsigned v1 = bt[aqv1 ^ akv ^ (unsigned)apt[s][d1]] & 1u;
                acc1 ^= v1;
            }
        }
        for (int s8 = 8; s8 < 16; ++s8) {      // j = 64..127: only upper query
            uint4 uk = *(const uint4*)&akT[s][s8 * 8];
            #pragma unroll
            for (int t = 0; t < 8; ++t) {
                int j = s8 * 8 + t;
                unsigned w = ((const unsigned*)&uk)[t >> 1];
                unsigned akv = (w >> ((t & 1) * 16)) & 0xffffu;
                int d1 = lane + 64 - j;        // <0 -> masked out
                unsigned v1 = bt[aqv1 ^ akv ^ (unsigned)apt[s][d1 & 127]] & 1u;
                acc1 ^= (d1 >= 0) ? v1 : 0u;
            }
        }
        rlo = __ballot(acc0 != 0u);
        rhi = __ballot(acc1 != 0u);
    }

    if (lane == 0) {
        pres[(size_t)r * 2 + 0] = rlo;
        pres[(size_t)r * 2 + 1] = rhi;
    }
}

__global__ __launch_bounds__(128) void vote_kernel(
    const unsigned long long* __restrict__ pres,  // [4096][2]
    int* __restrict__ out)                        // [S,B]
{
    const int n = blockIdx.x;              // 0..255
    const int i = threadIdx.x;             // 0..127
    const int w = i >> 6, b = i & 63;
    int tot = 0;
    #pragma unroll
    for (int h = 0; h < H; ++h)
        tot += (int)((pres[(size_t)(h * 256 + n) * 2 + w] >> b) & 1ull);
    out[i * B + n] = (tot > (H / 2)) ? 1 : 0;
}

extern "C" void kernel_launch(void* const* d_in, const int* in_sizes, int n_in,
                              void* d_out, int out_size, void* d_ws, size_t ws_size,
                              hipStream_t stream) {
    const int*   tokens      = (const int*)d_in[0];
    const float* memory      = (const float*)d_in[1];
    const int*   connections = (const int*)d_in[2];
    int*         out         = (int*)d_out;
    unsigned long long* pres = (unsigned long long*)d_ws;              // 64 KB @ 0
    unsigned*           tokP = (unsigned*)((char*)d_ws + (64u << 10)); // 4 KB @ 64K
    (void)in_sizes; (void)n_in; (void)out_size; (void)ws_size;

    pack_kernel<<<8, 256, 0, stream>>>(tokens, tokP);
    // 4096 rows, 2 rows/block (2 producer + 2 consumer waves) -> 2048 blocks
    softram_kernel<<<2048, 256, 0, stream>>>(tokP, memory, connections, pres);
    vote_kernel<<<B, 128, 0, stream>>>(pres, out);
}